// Round 1
// baseline (157.219 us; speedup 1.0000x reference)
//
#include <hip/hip_runtime.h>

#define NB 128
#define NS 8192
#define NK 16
#define NC 64          // chunks per sequence
#define NL (NS / NC)   // 128 steps per chunk

__device__ __forceinline__ float fexp2(float x) { return __builtin_amdgcn_exp2f(x); }
__device__ __forceinline__ float flog2(float x) { return __builtin_amdgcn_logf(x); }

__device__ __forceinline__ float gsum16(float v) {
    v += __shfl_xor(v, 1, 16);
    v += __shfl_xor(v, 2, 16);
    v += __shfl_xor(v, 4, 16);
    v += __shfl_xor(v, 8, 16);
    return v;
}
__device__ __forceinline__ float gmax16(float v) {
    v = fmaxf(v, __shfl_xor(v, 1, 16));
    v = fmaxf(v, __shfl_xor(v, 2, 16));
    v = fmaxf(v, __shfl_xor(v, 4, 16));
    v = fmaxf(v, __shfl_xor(v, 8, 16));
    return v;
}

// Phase 1: one thread per (b, chunk, row r). Evolves basis vector e_r through the
// chunk's steps in linear domain: W <- diag(lik_t) * A * W, A = amb*I + b*11^T.
// Result = column r of the chunk transfer matrix, stored so phase2 lane j reads
// contiguous {W_r[j]}_r.  Scale tracked as integer power of 2 (exact).
__global__ __launch_bounds__(256) void hmm_phase1(const float* __restrict__ obvs,
                                                  const float* __restrict__ mu,
                                                  const float* __restrict__ log_sigma,
                                                  float* __restrict__ wsW,
                                                  float* __restrict__ wsM) {
    const float LOG2E = 1.4426950408889634f;
    const float HLOG2PI = 0.918938533204672742f;  // 0.5*log(2*pi)
    int tid = blockIdx.x * blockDim.x + threadIdx.x;
    int r = tid & 15;
    int g = tid >> 4;          // g = b*NC + c
    int b = g >> 6;            // /NC
    int c = g & (NC - 1);

    // lik[k] = exp2(A2[k]*x^2 + B2[k]*x + C2[k])
    float A2[NK], B2[NK], C2[NK];
#pragma unroll
    for (int k = 0; k < NK; ++k) {
        float ls = log_sigma[k];
        float mk = mu[k];
        float iv = fexp2(-2.0f * LOG2E * ls);      // 1/sigma^2
        A2[k] = -0.5f * LOG2E * iv;
        B2[k] = LOG2E * mk * iv;
        C2[k] = LOG2E * (-0.5f * mk * mk * iv - ls - HLOG2PI);
    }

    float W[NK];
#pragma unroll
    for (int j = 0; j < NK; ++j) W[j] = (j == r) ? 1.0f : 0.0f;
    int ilog = 0;

    const float amb = 0.9f - 0.1f / 15.0f;   // stay - leak/(K-1)
    const float bco = 0.1f / 15.0f;          // leak/(K-1)

    const float* ob = obvs + (long)b * NS;
    int t0 = c * NL + (c == 0 ? 1 : 0);      // t=0 handled as init vector in phase2
    int t1 = c * NL + NL;

    float x = ob[t0];
    for (int t = t0; t < t1; ++t) {
        int tn = (t + 1 < t1) ? (t + 1) : (t1 - 1);
        float xn = ob[tn];                    // prefetch next observation
        float s0 = (W[0] + W[1]) + (W[2] + W[3]);
        float s1 = (W[4] + W[5]) + (W[6] + W[7]);
        float s2 = (W[8] + W[9]) + (W[10] + W[11]);
        float s3 = (W[12] + W[13]) + (W[14] + W[15]);
        float T = (s0 + s1) + (s2 + s3);
        if (T < 0x1p-40f) {                   // T only shrinks (lik<0.6); keep normal
#pragma unroll
            for (int j = 0; j < NK; ++j) W[j] *= 0x1p80f;
            T *= 0x1p80f;
            ilog -= 80;
        }
        float bT = bco * T;
#pragma unroll
        for (int j = 0; j < NK; ++j) {
            float lik = fexp2(fmaf(x, fmaf(x, A2[j], B2[j]), C2[j]));
            W[j] = fmaf(amb, W[j], bT) * lik;
        }
        x = xn;
    }

    // normalize chunk rows to the chunk's max row-scale (log2), store
    float s0 = (W[0] + W[1]) + (W[2] + W[3]);
    float s1 = (W[4] + W[5]) + (W[6] + W[7]);
    float s2 = (W[8] + W[9]) + (W[10] + W[11]);
    float s3 = (W[12] + W[13]) + (W[14] + W[15]);
    float Tf = (s0 + s1) + (s2 + s3);
    float lg = (float)ilog + flog2(Tf);       // true row scale (log2)
    float mx = gmax16(lg);                    // chunk max over the 16 rows
    float sc = fexp2((float)ilog - mx);       // W*sc = true column * 2^-mx
    float* dst = wsW + (long)g * 256 + r;     // layout [b][c][j][r]
#pragma unroll
    for (int j = 0; j < NK; ++j) dst[j * 16] = W[j] * sc;
    if (r == 0) wsM[g] = mx;
}

// Phase 2: 16 lanes per b. p init = lik(t=0)*softmax(prior); then sequentially
// apply the 64 chunk matrices with per-combine renormalization; answer_b = ln2*Plog.
__global__ __launch_bounds__(256) void hmm_phase2(const float* __restrict__ obvs,
                                                  const float* __restrict__ mu,
                                                  const float* __restrict__ log_sigma,
                                                  const float* __restrict__ prior_logits,
                                                  const float* __restrict__ wsW,
                                                  const float* __restrict__ wsM,
                                                  float* __restrict__ out) {
    const float LOG2E = 1.4426950408889634f;
    const float LN2 = 0.69314718055994531f;
    const float HLOG2PI = 0.918938533204672742f;
    int tid = blockIdx.x * blockDim.x + threadIdx.x;
    int j = tid & 15;    // state
    int b = tid >> 4;    // batch

    float ls = log_sigma[j];
    float mk = mu[j];
    float iv = fexp2(-2.0f * LOG2E * ls);
    float A2 = -0.5f * LOG2E * iv;
    float B2 = LOG2E * mk * iv;
    float C2 = LOG2E * (-0.5f * mk * mk * iv - ls - HLOG2PI);

    float x = obvs[(long)b * NS];             // t = 0
    float lik0 = fexp2(fmaf(x, fmaf(x, A2, B2), C2));
    float e = fexp2(LOG2E * prior_logits[j]); // = exp(prior_logits[j])
    float Z = gsum16(e);                      // softmax denominator
    float p = lik0 * e;
    float Plog = -flog2(Z);
    float T0 = gsum16(p);
    p /= T0;
    Plog += flog2(T0);

    for (int c = 0; c < NC; ++c) {
        const float4* col = reinterpret_cast<const float4*>(wsW + ((long)(b * NC + c)) * 256 + j * 16);
        float4 v0 = col[0];
        float4 v1 = col[1];
        float4 v2 = col[2];
        float4 v3 = col[3];
        float cw[16] = {v0.x, v0.y, v0.z, v0.w, v1.x, v1.y, v1.z, v1.w,
                        v2.x, v2.y, v2.z, v2.w, v3.x, v3.y, v3.z, v3.w};
        float q = 0.0f;
#pragma unroll
        for (int rr = 0; rr < 16; ++rr) {
            float pr = __shfl(p, rr, 16);
            q = fmaf(pr, cw[rr], q);
        }
        Plog += wsM[b * NC + c];
        float Tq = gsum16(q);
        p = q / Tq;
        Plog += flog2(Tq);
    }
    if (j == 0) atomicAdd(out, Plog * LN2);
}

extern "C" void kernel_launch(void* const* d_in, const int* in_sizes, int n_in,
                              void* d_out, int out_size, void* d_ws, size_t ws_size,
                              hipStream_t stream) {
    const float* obvs = (const float*)d_in[0];
    const float* mu = (const float*)d_in[1];
    const float* log_sigma = (const float*)d_in[2];
    const float* prior_logits = (const float*)d_in[3];
    float* out = (float*)d_out;
    float* wsW = (float*)d_ws;                       // NB*NC*256 floats = 8.39 MB
    float* wsM = wsW + (size_t)NB * NC * 256;        // NB*NC floats

    hipMemsetAsync(d_out, 0, sizeof(float), stream); // harness poisons d_out each call

    hmm_phase1<<<dim3(NB * NC * 16 / 256), dim3(256), 0, stream>>>(obvs, mu, log_sigma, wsW, wsM);
    hmm_phase2<<<dim3(NB * 16 / 256), dim3(256), 0, stream>>>(obvs, mu, log_sigma, prior_logits,
                                                              wsW, wsM, out);
}

// Round 2
// 124.147 us; speedup vs baseline: 1.2664x; 1.2664x over previous
//
#include <hip/hip_runtime.h>

#define NB 128
#define NS 8192
#define NK 16
#define NC 64          // chunks per sequence
#define NL (NS / NC)   // 128 steps per chunk

#define LOG2E 1.4426950408889634f
#define HLOG2PI 0.918938533204672742f
#define LN2 0.69314718055994531f

__device__ __forceinline__ float fexp2(float x) { return __builtin_amdgcn_exp2f(x); }
__device__ __forceinline__ float flog2(float x) { return __builtin_amdgcn_logf(x); }

__device__ __forceinline__ float gsum16(float v) {
    v += __shfl_xor(v, 1, 16);
    v += __shfl_xor(v, 2, 16);
    v += __shfl_xor(v, 4, 16);
    v += __shfl_xor(v, 8, 16);
    return v;
}
__device__ __forceinline__ float gmax16(float v) {
    v = fmaxf(v, __shfl_xor(v, 1, 16));
    v = fmaxf(v, __shfl_xor(v, 2, 16));
    v = fmaxf(v, __shfl_xor(v, 4, 16));
    v = fmaxf(v, __shfl_xor(v, 8, 16));
    return v;
}

// Phase 1: thread (b, chunk c, column r) evolves basis vector e_r through the
// chunk: W <- diag(lik_t) * A * W,  A = amb*I + bco*11^T.  Lane r computes only
// its OWN state's likelihood (1 exp) and the 16-lane group shares via bpermute.
__global__ __launch_bounds__(256) void hmm_phase1(const float* __restrict__ obvs,
                                                  const float* __restrict__ mu,
                                                  const float* __restrict__ log_sigma,
                                                  float* __restrict__ wsW,
                                                  float* __restrict__ wsM,
                                                  float* __restrict__ wsS,
                                                  float* __restrict__ out) {
    int tid = blockIdx.x * blockDim.x + threadIdx.x;
    if (tid == 0) out[0] = 0.0f;              // replaces memset dispatch (phase3 atomicAdds later)
    int r = tid & 15;
    int g = tid >> 4;          // g = b*NC + c
    int b = g >> 6;
    int c = g & (NC - 1);
    int lanebase = threadIdx.x & 48;          // 16-lane group base within wave

    // own-state emission coeffs: lik_r(x) = exp2(A2*x^2 + B2*x + C2)
    float ls = log_sigma[r];
    float mk = mu[r];
    float iv = fexp2(-2.0f * LOG2E * ls);     // 1/sigma^2
    float A2 = -0.5f * LOG2E * iv;
    float B2 = LOG2E * mk * iv;
    float C2 = LOG2E * (-0.5f * mk * mk * iv - ls - HLOG2PI);

    int bidx[16];
#pragma unroll
    for (int j = 0; j < 16; ++j) bidx[j] = (lanebase + j) << 2;  // bpermute byte addrs

    float W[16];
#pragma unroll
    for (int j = 0; j < 16; ++j) W[j] = (j == r) ? 1.0f : 0.0f;
    int ilog = 0;

    const float amb = 0.9f - 0.1f / 15.0f;
    const float bco = 0.1f / 15.0f;

    const float* ob = obvs + (long)b * NS;
    int t0 = c * NL + (c == 0 ? 1 : 0);       // t=0 handled as init vector in phase3
    int t1 = c * NL + NL;

    float x0 = ob[t0];
    float x1 = ob[(t0 + 1 < t1) ? t0 + 1 : t1 - 1];
    for (int t = t0; t < t1; ++t) {
        float xn = ob[(t + 2 < t1) ? (t + 2) : (t1 - 1)];   // 2-deep prefetch
        float s0 = (W[0] + W[1]) + (W[2] + W[3]);
        float s1 = (W[4] + W[5]) + (W[6] + W[7]);
        float s2 = (W[8] + W[9]) + (W[10] + W[11]);
        float s3 = (W[12] + W[13]) + (W[14] + W[15]);
        float T = (s0 + s1) + (s2 + s3);
        if (T < 0x1p-40f) {                    // T only shrinks; keep it normal
#pragma unroll
            for (int j = 0; j < 16; ++j) W[j] *= 0x1p80f;
            T *= 0x1p80f;
            ilog -= 80;
        }
        float myl = fexp2(fmaf(x0, fmaf(x0, A2, B2), C2));  // ONE exp per lane
        int mi = __float_as_int(myl);
        float bT = bco * T;
        float lk[16];
#pragma unroll
        for (int j = 0; j < 16; ++j)
            lk[j] = __int_as_float(__builtin_amdgcn_ds_bpermute(bidx[j], mi));
#pragma unroll
        for (int j = 0; j < 16; ++j) W[j] = fmaf(amb, W[j], bT) * lk[j];
        x0 = x1;
        x1 = xn;
    }

    // normalize chunk columns to the chunk's max column log-sum
    float s0 = (W[0] + W[1]) + (W[2] + W[3]);
    float s1 = (W[4] + W[5]) + (W[6] + W[7]);
    float s2 = (W[8] + W[9]) + (W[10] + W[11]);
    float s3 = (W[12] + W[13]) + (W[14] + W[15]);
    float Tf = (s0 + s1) + (s2 + s3);
    float lg = (float)ilog + flog2(Tf);
    float mx = gmax16(lg);
    float sc = fexp2((float)ilog - mx);
    float* dst = wsW + (long)g * 256 + r;      // layout [g][j][r]
#pragma unroll
    for (int j = 0; j < 16; ++j) dst[j * 16] = W[j] * sc;
    wsS[g * 16 + r] = Tf * sc;                 // column sums (max over r == 1)
    if (r == 0) wsM[g] = mx;
}

// Phase 2: one block per (b, half). Stages 32 chunk matrices + colsums into LDS,
// tree-combines 5 levels (later*earlier) with per-level max-colsum rescaling.
// Writes one combined matrix + its log2-scale per (b, half).
__global__ __launch_bounds__(256) void hmm_phase2(const float* __restrict__ wsW,
                                                  const float* __restrict__ wsM,
                                                  const float* __restrict__ wsS,
                                                  float* __restrict__ wsW2,
                                                  float* __restrict__ wsM2) {
    __shared__ float X[32 * 256];   // 32 KB
    __shared__ float Y[16 * 256];   // 16 KB
    __shared__ float csX[32 * 16];
    __shared__ float csY[16 * 16];
    __shared__ float invS[16];
    __shared__ float smM[32];
    __shared__ float logAcc;

    int bi = blockIdx.x;            // 0..255
    int b = bi >> 1;
    int c0 = (bi & 1) * 32;
    int tid = threadIdx.x;

    const float4* src = (const float4*)(wsW + ((long)b * NC + c0) * 256);
    float4* dstX = (float4*)X;
    for (int i = tid; i < 2048; i += 256) dstX[i] = src[i];
    for (int i = tid; i < 512; i += 256) csX[i] = wsS[(b * NC + c0) * 16 + i];
    if (tid < 32) smM[tid] = wsM[b * NC + c0 + tid];
    if (tid == 0) logAcc = 0.0f;
    __syncthreads();

    float* cur = X; float* nxt = Y;
    float* ccs = csX; float* ncs = csY;
    int npairs = 16;
    for (int l = 0; l < 5; ++l) {
        // step A: colsums of products + per-pair rescale factor
        {
            int i0 = tid >> 4, r = tid & 15;
            for (int i = i0; i < npairs; i += 16) {
                const float* Ma = cur + (2 * i) * 256;
                const float* cb = ccs + (2 * i + 1) * 16;
                float s = 0.0f;
#pragma unroll
                for (int k = 0; k < 16; ++k) s = fmaf(cb[k], Ma[k * 16 + r], s);
                float S = gmax16(s);
                float is = 1.0f / S;
                ncs[i * 16 + r] = s * is;
                if (r == 0) { invS[i] = is; atomicAdd(&logAcc, flog2(S)); }
            }
        }
        __syncthreads();
        // step B: P = Mb * Ma, normalized
        {
            int j = tid >> 4, r = tid & 15;
            for (int i = 0; i < npairs; ++i) {
                const float* Ma = cur + (2 * i) * 256;
                const float* Mb = cur + (2 * i + 1) * 256 + j * 16;
                float br[16];
                *(float4*)&br[0]  = ((const float4*)Mb)[0];
                *(float4*)&br[4]  = ((const float4*)Mb)[1];
                *(float4*)&br[8]  = ((const float4*)Mb)[2];
                *(float4*)&br[12] = ((const float4*)Mb)[3];
                float acc = br[0] * Ma[r];
#pragma unroll
                for (int k = 1; k < 16; ++k) acc = fmaf(br[k], Ma[k * 16 + r], acc);
                nxt[i * 256 + tid] = acc * invS[i];
            }
        }
        __syncthreads();
        float* t1 = cur; cur = nxt; nxt = t1;
        float* t2 = ccs; ccs = ncs; ncs = t2;
        npairs >>= 1;
    }
    // cur holds the combined half-matrix (slot 0)
    wsW2[(long)bi * 256 + tid] = cur[tid];
    if (tid < 16) {
        float pm = smM[tid] + smM[tid + 16];
        pm = gsum16(pm);
        if (tid == 0) wsM2[bi] = pm + logAcc;
    }
}

// Phase 3: 16 lanes per b — init vector, apply the 2 half-matrices, logsumexp.
__global__ __launch_bounds__(256) void hmm_phase3(const float* __restrict__ obvs,
                                                  const float* __restrict__ mu,
                                                  const float* __restrict__ log_sigma,
                                                  const float* __restrict__ prior_logits,
                                                  const float* __restrict__ wsW2,
                                                  const float* __restrict__ wsM2,
                                                  float* __restrict__ out) {
    int tid = blockIdx.x * blockDim.x + threadIdx.x;
    int j = tid & 15;
    int b = tid >> 4;

    float ls = log_sigma[j];
    float mk = mu[j];
    float iv = fexp2(-2.0f * LOG2E * ls);
    float A2 = -0.5f * LOG2E * iv;
    float B2 = LOG2E * mk * iv;
    float C2 = LOG2E * (-0.5f * mk * mk * iv - ls - HLOG2PI);

    float x = obvs[(long)b * NS];
    float lik0 = fexp2(fmaf(x, fmaf(x, A2, B2), C2));
    float e = fexp2(LOG2E * prior_logits[j]);
    float Z = gsum16(e);
    float p = lik0 * e;
    float Plog = -flog2(Z);

    for (int h = 0; h < 2; ++h) {
        const float* M = wsW2 + (long)(b * 2 + h) * 256 + j * 16;
        float mr[16];
        *(float4*)&mr[0]  = ((const float4*)M)[0];
        *(float4*)&mr[4]  = ((const float4*)M)[1];
        *(float4*)&mr[8]  = ((const float4*)M)[2];
        *(float4*)&mr[12] = ((const float4*)M)[3];
        float q = 0.0f;
#pragma unroll
        for (int rr = 0; rr < 16; ++rr) q = fmaf(mr[rr], __shfl(p, rr, 16), q);
        float Tq = gsum16(q);
        p = q / Tq;
        Plog += flog2(Tq) + wsM2[b * 2 + h];
    }
    if (j == 0) atomicAdd(out, Plog * LN2);
}

extern "C" void kernel_launch(void* const* d_in, const int* in_sizes, int n_in,
                              void* d_out, int out_size, void* d_ws, size_t ws_size,
                              hipStream_t stream) {
    const float* obvs = (const float*)d_in[0];
    const float* mu = (const float*)d_in[1];
    const float* log_sigma = (const float*)d_in[2];
    const float* prior_logits = (const float*)d_in[3];
    float* out = (float*)d_out;

    float* wsW = (float*)d_ws;                         // 128*64*256 = 2,097,152 f
    float* wsM = wsW + (size_t)NB * NC * 256;          // 8192 f
    float* wsS = wsM + (size_t)NB * NC;                // 131072 f
    float* wsW2 = wsS + (size_t)NB * NC * 16;          // 65536 f
    float* wsM2 = wsW2 + (size_t)NB * 2 * 256;         // 256 f

    hmm_phase1<<<dim3(NB * NC * 16 / 256), dim3(256), 0, stream>>>(obvs, mu, log_sigma,
                                                                   wsW, wsM, wsS, out);
    hmm_phase2<<<dim3(NB * 2), dim3(256), 0, stream>>>(wsW, wsM, wsS, wsW2, wsM2);
    hmm_phase3<<<dim3(NB * 16 / 256), dim3(256), 0, stream>>>(obvs, mu, log_sigma, prior_logits,
                                                              wsW2, wsM2, out);
}